// Round 3
// baseline (46131.464 us; speedup 1.0000x reference)
//
#include <hip/hip_runtime.h>

#define NELEM     16777216   // 64^4
#define CI_STRIDE 262144     // 64^3
#define WTP_PASS  36864      // 64ci * 3 * 3 * 64co
#define NFLAG     (6 * 256 * 16)
#define EX_SLOT   768        // 12 border px * 64 ch per block
#define EX_STEP   (256 * EX_SLOT)

__device__ float    g_bufA[NELEM + 32];
__device__ float    g_bufB[NELEM + 32];
__device__ float    g_wtp[6 * WTP_PASS];
__device__ float    g_exch[64 * EX_STEP];   // halo exchange, slot = step
__device__ unsigned g_flags[NFLAG];

__device__ __forceinline__ float ald(const float* p) {
    return __hip_atomic_load(p, __ATOMIC_RELAXED, __HIP_MEMORY_SCOPE_AGENT);
}
__device__ __forceinline__ void ast(float* p, float v) {
    __hip_atomic_store(p, v, __ATOMIC_RELAXED, __HIP_MEMORY_SCOPE_AGENT);
}

// Weight prep: g_wtp[p][((ci*3+ky)*3+kx)*64+co]; passes 4,5 spatially transposed.
// Also zeroes all sync flags.
__global__ __launch_bounds__(256) void prep(
    const float* __restrict__ w0, const float* __restrict__ w1,
    const float* __restrict__ w2, const float* __restrict__ w3,
    const float* __restrict__ w4, const float* __restrict__ w5)
{
    int gid = blockIdx.x * 256 + threadIdx.x;
    if (gid < NFLAG) g_flags[gid] = 0;
    if (gid >= 6 * WTP_PASS) return;
    int p  = gid / WTP_PASS;
    int r  = gid % WTP_PASS;
    int co = r & 63;
    int q  = r >> 6;          // ci*9 + ky*3 + kx
    int kx = q % 3;
    int t2 = q / 3;
    int ky = t2 % 3;
    int ci = t2 / 3;
    const float* src = (p==0)?w0:(p==1)?w1:(p==2)?w2:(p==3)?w3:(p==4)?w4:w5;
    g_wtp[gid] = (p < 4) ? src[co*576 + ci*9 + ky*3 + kx]
                         : src[co*576 + ci*9 + kx*3 + ky];
}

__global__ __launch_bounds__(256) void transpose_hw(
    const float* __restrict__ in, float* __restrict__ out)
{
    __shared__ float t[64][65];
    const size_t base = (size_t)blockIdx.x * 4096;
    const int c  = threadIdx.x & 63;
    const int r4 = threadIdx.x >> 6;
#pragma unroll
    for (int r = 0; r < 16; ++r) {
        int a = r4 * 16 + r;
        t[a][c] = in[base + a * 64 + c];
    }
    __syncthreads();
#pragma unroll
    for (int r = 0; r < 16; ++r) {
        int bb = r4 * 16 + r;
        out[base + (size_t)bb * 64 + c] = t[c][bb];
    }
}

// Border px index within a 4x4 tile: r0 -> 0..3, r3 -> 4..7,
// (1,0)=8 (2,0)=9 (1,3)=10 (2,3)=11
__constant__ int idxL[4] = {3, 10, 11, 7};   // left nbr px (r,3)
__constant__ int idxR[4] = {0, 8, 9, 4};     // right nbr px (r,0)

// Persistent per-pass scan kernel. Block = 4x4 px tile x 64 co; wave = 16-ci
// chunk (lane = co, weights in VGPRs). Halo via coherent exchange buffer;
// NO device fences (interior reads are own-CU writes; halo bypasses L2).
__global__ __launch_bounds__(256, 1) void pass_kernel(
    float* __restrict__ buf, const float* __restrict__ wtp,
    unsigned* __restrict__ flags, float* __restrict__ exch,
    int st, int su, int dir)
{
    __shared__ float red[21504];   // 84 KB -> exactly 1 block/CU
    const int tid  = threadIdx.x;
    const int lane = tid & 63;
    const int wv   = tid >> 6;
    const int b    = blockIdx.x;
    const int bu   = b >> 4, bv = b & 15;
    const int u0   = bu << 2, v0 = bv << 2;
    const bool vU = (bu > 0), vD = (bu < 15), vL = (bv > 0), vR = (bv < 15);
    const int oU  = ((bu-1)*16 + bv    ) * EX_SLOT;
    const int oD  = ((bu+1)*16 + bv    ) * EX_SLOT;
    const int oL  = ((bu  )*16 + bv - 1) * EX_SLOT;
    const int oR  = ((bu  )*16 + bv + 1) * EX_SLOT;
    const int oUL = oU - EX_SLOT, oUR = oU + EX_SLOT;
    const int oDL = oD - EX_SLOT, oDR = oD + EX_SLOT;

    // per-lane weights for this wave's 16 ci (loaded once per pass)
    float W[16][3][3];
#pragma unroll
    for (int i = 0; i < 16; ++i)
#pragma unroll
        for (int ky = 0; ky < 3; ++ky)
#pragma unroll
            for (int kx = 0; kx < 3; ++kx)
                W[i][ky][kx] = wtp[(((wv*16 + i)*3 + ky)*3 + kx)*64 + lane];

    // lanes 0..7 of wave 0 each own one spatial neighbor's flag
    int nbr = -1;
    if (lane < 8) {
        int c  = lane + (lane >= 4 ? 1 : 0);
        int nu = bu + c/3 - 1, nv = bv + c%3 - 1;
        if (nu >= 0 && nu < 16 && nv >= 0 && nv < 16) nbr = (nu*16 + nv)*16;
    }

    for (int s = 1; s <= 63; ++s) {
        const int t  = (dir > 0) ? s : 63 - s;
        const int tp = t - dir;

        if (s > 1) {
            if (wv == 0) {
                const unsigned tgt = (unsigned)(s - 1);
                bool ok = (nbr < 0);
                int spins = 0;
                while (!__all(ok) && spins < (1 << 24)) {
                    if (!ok) ok = __hip_atomic_load(&flags[nbr], __ATOMIC_RELAXED,
                                                    __HIP_MEMORY_SCOPE_AGENT) >= tgt;
                    ++spins;
                }
            }
            __syncthreads();
        }

        const float* prev = buf + (size_t)tp * st;
        const float* xs   = exch + (size_t)(s - 1) * EX_STEP;
        float acc[4][4] = {{0.f}};

        if (s == 1) {
            // ring + interior all from buf (pre-pass data, fresh at dispatch)
#pragma unroll
            for (int i = 0; i < 16; ++i) {
                const float* cb = prev + (size_t)(wv*16 + i) * CI_STRIDE;
                float win[6][6];
#pragma unroll
                for (int r = 0; r < 6; ++r) {
                    const int uu = u0 - 1 + r;
                    if (uu >= 0 && uu <= 63) {
                        const float* rp = cb + (size_t)uu * su + v0;
                        float4 m = *(const float4*)rp;
                        win[r][0] = (v0 != 0)  ? rp[-1] : 0.f;
                        win[r][5] = (v0 != 60) ? rp[4]  : 0.f;
                        win[r][1] = m.x; win[r][2] = m.y; win[r][3] = m.z; win[r][4] = m.w;
                    } else {
                        win[r][0]=win[r][1]=win[r][2]=win[r][3]=win[r][4]=win[r][5]=0.f;
                    }
                }
#pragma unroll
                for (int oi = 0; oi < 4; ++oi)
#pragma unroll
                    for (int ky = 0; ky < 3; ++ky) {
                        const float k0 = W[i][ky][0], k1 = W[i][ky][1], k2 = W[i][ky][2];
#pragma unroll
                        for (int oj = 0; oj < 4; ++oj)
                            acc[oi][oj] = fmaf(win[oi+ky][oj],   k0,
                                          fmaf(win[oi+ky][oj+1], k1,
                                          fmaf(win[oi+ky][oj+2], k2, acc[oi][oj])));
                    }
            }
        } else {
            // interior (own tile, own-CU writes from step s-1) from buf;
            // ring from coherent exchange slot s-1
#pragma unroll
            for (int i = 0; i < 16; ++i) {
                const int ci = wv*16 + i;
                const float* cb = prev + (size_t)ci * CI_STRIDE;
                float win[6][6];
#pragma unroll
                for (int r = 0; r < 4; ++r) {
                    const float* rp = cb + (size_t)(u0 + r) * su + v0;
                    float4 m = *(const float4*)rp;
                    win[r+1][1] = m.x; win[r+1][2] = m.y;
                    win[r+1][3] = m.z; win[r+1][4] = m.w;
                    win[r+1][0] = vL ? ald(xs + oL + idxL[r]*64 + ci) : 0.f;
                    win[r+1][5] = vR ? ald(xs + oR + idxR[r]*64 + ci) : 0.f;
                }
                if (vU) {
#pragma unroll
                    for (int c = 0; c < 4; ++c)
                        win[0][1+c] = ald(xs + oU + (4+c)*64 + ci);
                    win[0][0] = vL ? ald(xs + oUL + 7*64 + ci) : 0.f;
                    win[0][5] = vR ? ald(xs + oUR + 4*64 + ci) : 0.f;
                } else {
                    win[0][0]=win[0][1]=win[0][2]=win[0][3]=win[0][4]=win[0][5]=0.f;
                }
                if (vD) {
#pragma unroll
                    for (int c = 0; c < 4; ++c)
                        win[5][1+c] = ald(xs + oD + c*64 + ci);
                    win[5][0] = vL ? ald(xs + oDL + 3*64 + ci) : 0.f;
                    win[5][5] = vR ? ald(xs + oDR + 0*64 + ci) : 0.f;
                } else {
                    win[5][0]=win[5][1]=win[5][2]=win[5][3]=win[5][4]=win[5][5]=0.f;
                }
#pragma unroll
                for (int oi = 0; oi < 4; ++oi)
#pragma unroll
                    for (int ky = 0; ky < 3; ++ky) {
                        const float k0 = W[i][ky][0], k1 = W[i][ky][1], k2 = W[i][ky][2];
#pragma unroll
                        for (int oj = 0; oj < 4; ++oj)
                            acc[oi][oj] = fmaf(win[oi+ky][oj],   k0,
                                          fmaf(win[oi+ky][oj+1], k1,
                                          fmaf(win[oi+ky][oj+2], k2, acc[oi][oj])));
                    }
            }
        }

        // cross-wave ci-reduction via LDS
#pragma unroll
        for (int oi = 0; oi < 4; ++oi)
#pragma unroll
            for (int oj = 0; oj < 4; ++oj)
                red[(wv*16 + oi*4 + oj)*64 + lane] = acc[oi][oj];
        __syncthreads();

        float s0=0.f, s1=0.f, s2=0.f, s3=0.f;
#pragma unroll
        for (int j2 = 0; j2 < 4; ++j2) {
            s0 += red[(j2*16 + wv*4 + 0)*64 + lane];
            s1 += red[(j2*16 + wv*4 + 1)*64 + lane];
            s2 += red[(j2*16 + wv*4 + 2)*64 + lane];
            s3 += red[(j2*16 + wv*4 + 3)*64 + lane];
        }
        // wave wv owns output row u0+wv, cols v0..v0+3
        float* cp = buf + (size_t)t*st + (size_t)lane*CI_STRIDE
                  + (size_t)(u0+wv)*su + v0;
        float4 c = *(float4*)cp;
        c.x += fmaxf(s0, 0.f); c.y += fmaxf(s1, 0.f);
        c.z += fmaxf(s2, 0.f); c.w += fmaxf(s3, 0.f);
        *(float4*)cp = c;

        // publish border px of this tile row to exchange slot s (coherent)
        float* eb = exch + (size_t)s * EX_STEP + b * EX_SLOT;
        if (wv == 0) {
            ast(eb + 0*64 + lane, c.x); ast(eb + 1*64 + lane, c.y);
            ast(eb + 2*64 + lane, c.z); ast(eb + 3*64 + lane, c.w);
        } else if (wv == 3) {
            ast(eb + 4*64 + lane, c.x); ast(eb + 5*64 + lane, c.y);
            ast(eb + 6*64 + lane, c.z); ast(eb + 7*64 + lane, c.w);
        } else if (wv == 1) {
            ast(eb + 8*64 + lane, c.x); ast(eb + 10*64 + lane, c.w);
        } else {
            ast(eb + 9*64 + lane, c.x); ast(eb + 11*64 + lane, c.w);
        }
        __syncthreads();   // drains vmcnt(0) in every wave before flag publish

        if (tid == 0)
            __hip_atomic_store(&flags[b*16], (unsigned)s, __ATOMIC_RELAXED,
                               __HIP_MEMORY_SCOPE_AGENT);
    }
}

extern "C" void kernel_launch(void* const* d_in, const int* in_sizes, int n_in,
                              void* d_out, int out_size, void* d_ws, size_t ws_size,
                              hipStream_t stream)
{
    (void)in_sizes; (void)n_in; (void)out_size; (void)d_ws; (void)ws_size;
    const float* x = (const float*)d_in[0];
    float* out = (float*)d_out;

    void *pa, *pb, *pw, *pf, *pe;
    hipGetSymbolAddress(&pa, HIP_SYMBOL(g_bufA));
    hipGetSymbolAddress(&pb, HIP_SYMBOL(g_bufB));
    hipGetSymbolAddress(&pw, HIP_SYMBOL(g_wtp));
    hipGetSymbolAddress(&pf, HIP_SYMBOL(g_flags));
    hipGetSymbolAddress(&pe, HIP_SYMBOL(g_exch));
    float* A = (float*)pa + 16;
    float* B = (float*)pb + 16;
    float* wtp = (float*)pw;
    unsigned* flags = (unsigned*)pf;
    float* exch = (float*)pe;

    prep<<<864, 256, 0, stream>>>(
        (const float*)d_in[1], (const float*)d_in[2], (const float*)d_in[3],
        (const float*)d_in[4], (const float*)d_in[5], (const float*)d_in[6]);

    hipMemcpyAsync(A, x, (size_t)NELEM * sizeof(float),
                   hipMemcpyDeviceToDevice, stream);

    // layout0 [k][d][h][w]: UD/DU: t=h (st 64), u=d (su 4096), v=w
    pass_kernel<<<256, 256, 0, stream>>>(A, wtp + 0*WTP_PASS, flags + 0*4096, exch, 64, 4096, +1);
    pass_kernel<<<256, 256, 0, stream>>>(A, wtp + 1*WTP_PASS, flags + 1*4096, exch, 64, 4096, -1);

    transpose_hw<<<4096, 256, 0, stream>>>(A, B);   // -> layout1 [k][d][w][h]

    // LR/RL: t=w (st 64), u=d (su 4096), v=h
    pass_kernel<<<256, 256, 0, stream>>>(B, wtp + 2*WTP_PASS, flags + 2*4096, exch, 64, 4096, +1);
    pass_kernel<<<256, 256, 0, stream>>>(B, wtp + 3*WTP_PASS, flags + 3*4096, exch, 64, 4096, -1);
    // FB/BF: t=d (st 4096), u=w (su 64), v=h; weights spatially transposed
    pass_kernel<<<256, 256, 0, stream>>>(B, wtp + 4*WTP_PASS, flags + 4*4096, exch, 4096, 64, +1);
    pass_kernel<<<256, 256, 0, stream>>>(B, wtp + 5*WTP_PASS, flags + 5*4096, exch, 4096, 64, -1);

    transpose_hw<<<4096, 256, 0, stream>>>(B, out);
}

// Round 4
// 9626.675 us; speedup vs baseline: 4.7920x; 4.7920x over previous
//
#include <hip/hip_runtime.h>

#define NELEM     16777216   // 64^4
#define CI_STRIDE 262144     // 64^3
#define WTP_PASS  36864      // 64ci * 3 * 3 * 64co
#define NFLAG     (6 * 256 * 16)

__device__ float    g_bufA[NELEM + 32];
__device__ float    g_bufB[NELEM + 32];
__device__ float    g_wtp[6 * WTP_PASS];
__device__ unsigned g_flags[NFLAG];

// 8B L3-coherent load/store (bypass L1/L2; meet at Infinity Cache).
__device__ __forceinline__ float2 ld2cc(const float* p) {
    unsigned long long u = __hip_atomic_load((const unsigned long long*)p,
                            __ATOMIC_RELAXED, __HIP_MEMORY_SCOPE_AGENT);
    float2 r;
    r.x = __uint_as_float((unsigned)u);
    r.y = __uint_as_float((unsigned)(u >> 32));
    return r;
}
__device__ __forceinline__ void st2cc(float* p, float a, float b) {
    unsigned long long u = ((unsigned long long)__float_as_uint(b) << 32)
                         | (unsigned long long)__float_as_uint(a);
    __hip_atomic_store((unsigned long long*)p, u,
                       __ATOMIC_RELAXED, __HIP_MEMORY_SCOPE_AGENT);
}

// Weight prep: g_wtp[p][((ci*3+ky)*3+kx)*64+co]; passes 4,5 spatially
// transposed. Also zeroes all sync flags.
__global__ __launch_bounds__(256) void prep(
    const float* __restrict__ w0, const float* __restrict__ w1,
    const float* __restrict__ w2, const float* __restrict__ w3,
    const float* __restrict__ w4, const float* __restrict__ w5)
{
    int gid = blockIdx.x * 256 + threadIdx.x;
    if (gid < NFLAG) g_flags[gid] = 0;
    if (gid >= 6 * WTP_PASS) return;
    int p  = gid / WTP_PASS;
    int r  = gid % WTP_PASS;
    int co = r & 63;
    int q  = r >> 6;          // ci*9 + ky*3 + kx
    int kx = q % 3;
    int t2 = q / 3;
    int ky = t2 % 3;
    int ci = t2 / 3;
    const float* src = (p==0)?w0:(p==1)?w1:(p==2)?w2:(p==3)?w3:(p==4)?w4:w5;
    g_wtp[gid] = (p < 4) ? src[co*576 + ci*9 + ky*3 + kx]
                         : src[co*576 + ci*9 + kx*3 + ky];
}

__global__ __launch_bounds__(256) void transpose_hw(
    const float* __restrict__ in, float* __restrict__ out)
{
    __shared__ float t[64][65];
    const size_t base = (size_t)blockIdx.x * 4096;
    const int c  = threadIdx.x & 63;
    const int r4 = threadIdx.x >> 6;
#pragma unroll
    for (int r = 0; r < 16; ++r) {
        int a = r4 * 16 + r;
        t[a][c] = in[base + a * 64 + c];
    }
    __syncthreads();
#pragma unroll
    for (int r = 0; r < 16; ++r) {
        int bb = r4 * 16 + r;
        out[base + (size_t)bb * 64 + c] = t[c][bb];
    }
}

// Persistent per-pass scan. Block = 4x4 px tile x 64 co; 8 waves, wave = 8-ci
// chunk (lane = co, weights in VGPRs, 2 waves/SIMD). All slice reads/writes
// inside the scan go through L3-coherent 8B ops -> no fences, XCD-agnostic.
__global__ __launch_bounds__(512, 2) void pass_kernel(
    float* __restrict__ buf, const float* __restrict__ wtp,
    unsigned* __restrict__ flags, int st, int su, int dir)
{
    __shared__ float red[21504];   // 84 KB -> exactly 1 block/CU (all resident)
    const int tid  = threadIdx.x;
    const int lane = tid & 63;
    const int wv   = tid >> 6;     // 0..7
    const int b    = blockIdx.x;
    const int bu   = b >> 4, bv = b & 15;
    const int u0   = bu << 2, v0 = bv << 2;
    const bool vL  = (v0 != 0), vR = (v0 != 60);

    // per-lane weights for this wave's 8 ci (loaded once per pass)
    float W[8][3][3];
#pragma unroll
    for (int i = 0; i < 8; ++i)
#pragma unroll
        for (int ky = 0; ky < 3; ++ky)
#pragma unroll
            for (int kx = 0; kx < 3; ++kx)
                W[i][ky][kx] = wtp[(((wv*8 + i)*3 + ky)*3 + kx)*64 + lane];

    // lanes 0..7 of wave 0 each own one spatial neighbor's flag
    int nbr = -1;
    if (lane < 8) {
        int c  = lane + (lane >= 4 ? 1 : 0);   // skip center of 3x3
        int nu = bu + c/3 - 1, nv = bv + c%3 - 1;
        if (nu >= 0 && nu < 16 && nv >= 0 && nv < 16) nbr = (nu*16 + nv)*16;
    }

    for (int s = 1; s <= 63; ++s) {
        const int t  = (dir > 0) ? s : 63 - s;
        const int tp = t - dir;

        // wait until all 8 neighbors have completed step s-1 (throttled polls)
        if (wv == 0 && s > 1) {
            const unsigned tgt = (unsigned)(s - 1);
            bool ok = (nbr < 0);
            if (!ok) ok = __hip_atomic_load(&flags[nbr], __ATOMIC_RELAXED,
                                            __HIP_MEMORY_SCOPE_AGENT) >= tgt;
            int spins = 0;
            while (!__all(ok) && spins < (1 << 22)) {
                __builtin_amdgcn_s_sleep(1);
                if (!ok) ok = __hip_atomic_load(&flags[nbr], __ATOMIC_RELAXED,
                                                __HIP_MEMORY_SCOPE_AGENT) >= tgt;
                ++spins;
            }
        }
        __syncthreads();

        const float* prev = buf + (size_t)tp * st;
        float acc[16];
#pragma unroll
        for (int p = 0; p < 16; ++p) acc[p] = 0.f;

#pragma unroll 4
        for (int i = 0; i < 8; ++i) {
            const int ci = wv*8 + i;
            const float* cb = prev + (size_t)ci * CI_STRIDE;
            float win[6][6];
#pragma unroll
            for (int r = 0; r < 6; ++r) {
                const int uu = u0 - 1 + r;
                if (uu >= 0 && uu <= 63) {
                    const float* rp = cb + (size_t)uu * su + v0;
                    float2 a = ld2cc(rp - 2);
                    float2 m0 = ld2cc(rp);
                    float2 m1 = ld2cc(rp + 2);
                    float2 d = ld2cc(rp + 4);
                    win[r][0] = vL ? a.y : 0.f;
                    win[r][1] = m0.x; win[r][2] = m0.y;
                    win[r][3] = m1.x; win[r][4] = m1.y;
                    win[r][5] = vR ? d.x : 0.f;
                } else {
                    win[r][0]=win[r][1]=win[r][2]=win[r][3]=win[r][4]=win[r][5]=0.f;
                }
            }
#pragma unroll
            for (int oi = 0; oi < 4; ++oi)
#pragma unroll
                for (int ky = 0; ky < 3; ++ky) {
                    const float k0 = W[i][ky][0], k1 = W[i][ky][1], k2 = W[i][ky][2];
#pragma unroll
                    for (int oj = 0; oj < 4; ++oj)
                        acc[oi*4+oj] = fmaf(win[oi+ky][oj],   k0,
                                       fmaf(win[oi+ky][oj+1], k1,
                                       fmaf(win[oi+ky][oj+2], k2, acc[oi*4+oj])));
                }
        }

        // cross-wave ci-reduction via LDS (8 partials per px)
#pragma unroll
        for (int p = 0; p < 16; ++p)
            red[(wv*16 + p)*64 + lane] = acc[p];
        __syncthreads();

        // wave wv owns px pair p = 2*wv, 2*wv+1 (row = wv>>1, cols (wv&1)*2..+1)
        float s0 = 0.f, s1 = 0.f;
#pragma unroll
        for (int g = 0; g < 8; ++g) {
            s0 += red[(g*16 + wv*2 + 0)*64 + lane];
            s1 += red[(g*16 + wv*2 + 1)*64 + lane];
        }
        const int row = wv >> 1, c0 = (wv & 1) * 2;
        float* cp = buf + (size_t)t*st + (size_t)lane*CI_STRIDE
                  + (size_t)(u0+row)*su + (v0 + c0);
        float2 o = *(const float2*)cp;          // pre-pass x[t] (plain: L3-fresh)
        st2cc(cp, o.x + fmaxf(s0, 0.f), o.y + fmaxf(s1, 0.f));
        __syncthreads();   // drains vmcnt(0) in every wave before flag publish

        if (tid == 0)
            __hip_atomic_store(&flags[b*16], (unsigned)s, __ATOMIC_RELAXED,
                               __HIP_MEMORY_SCOPE_AGENT);
    }
}

extern "C" void kernel_launch(void* const* d_in, const int* in_sizes, int n_in,
                              void* d_out, int out_size, void* d_ws, size_t ws_size,
                              hipStream_t stream)
{
    (void)in_sizes; (void)n_in; (void)out_size; (void)d_ws; (void)ws_size;
    const float* x = (const float*)d_in[0];
    float* out = (float*)d_out;

    void *pa, *pb, *pw, *pf;
    hipGetSymbolAddress(&pa, HIP_SYMBOL(g_bufA));
    hipGetSymbolAddress(&pb, HIP_SYMBOL(g_bufB));
    hipGetSymbolAddress(&pw, HIP_SYMBOL(g_wtp));
    hipGetSymbolAddress(&pf, HIP_SYMBOL(g_flags));
    float* A = (float*)pa + 16;   // 64B-aligned; pad covers col -2 loads
    float* B = (float*)pb + 16;
    float* wtp = (float*)pw;
    unsigned* flags = (unsigned*)pf;

    prep<<<864, 256, 0, stream>>>(
        (const float*)d_in[1], (const float*)d_in[2], (const float*)d_in[3],
        (const float*)d_in[4], (const float*)d_in[5], (const float*)d_in[6]);

    hipMemcpyAsync(A, x, (size_t)NELEM * sizeof(float),
                   hipMemcpyDeviceToDevice, stream);

    // layout0 [k][d][h][w]: UD/DU: t=h (st 64), u=d (su 4096), v=w
    pass_kernel<<<256, 512, 0, stream>>>(A, wtp + 0*WTP_PASS, flags + 0*4096, 64, 4096, +1);
    pass_kernel<<<256, 512, 0, stream>>>(A, wtp + 1*WTP_PASS, flags + 1*4096, 64, 4096, -1);

    transpose_hw<<<4096, 256, 0, stream>>>(A, B);   // -> layout1 [k][d][w][h]

    // LR/RL: t=w (st 64), u=d (su 4096), v=h
    pass_kernel<<<256, 512, 0, stream>>>(B, wtp + 2*WTP_PASS, flags + 2*4096, 64, 4096, +1);
    pass_kernel<<<256, 512, 0, stream>>>(B, wtp + 3*WTP_PASS, flags + 3*4096, 64, 4096, -1);
    // FB/BF: t=d (st 4096), u=w (su 64), v=h; weights spatially transposed
    pass_kernel<<<256, 512, 0, stream>>>(B, wtp + 4*WTP_PASS, flags + 4*4096, 4096, 64, +1);
    pass_kernel<<<256, 512, 0, stream>>>(B, wtp + 5*WTP_PASS, flags + 5*4096, 4096, 64, -1);

    transpose_hw<<<4096, 256, 0, stream>>>(B, out);
}

// Round 5
// 3143.034 us; speedup vs baseline: 14.6774x; 3.0629x over previous
//
#include <hip/hip_runtime.h>

#define NELEM     16777216   // 64^4
#define CI_STRIDE 262144     // 64^3
#define WTP_PASS  36864      // 64ci * 3 * 3 * 64co
#define NFLAG     (6 * 256 * 16)
#define EXN       (2 * 256 * 16 * 64)   // [parity][block][px16][ch64]

__device__ float    g_bufA[NELEM + 32];
__device__ float    g_bufB[NELEM + 32];
__device__ float    g_wtp[6 * WTP_PASS];
__device__ float    g_exch[EXN];
__device__ unsigned g_flags[NFLAG];

// halo ring of the 6x6 region: 20 entries (row,col)
__constant__ signed char HROW[20] = {0,0,0,0,0,0, 5,5,5,5,5,5, 1,2,3,4, 1,2,3,4};
__constant__ signed char HCOL[20] = {0,1,2,3,4,5, 0,1,2,3,4,5, 0,0,0,0, 5,5,5,5};

__device__ __forceinline__ float ald(const float* p) {
    return __hip_atomic_load(p, __ATOMIC_RELAXED, __HIP_MEMORY_SCOPE_AGENT);
}
__device__ __forceinline__ void ast(float* p, float v) {
    __hip_atomic_store(p, v, __ATOMIC_RELAXED, __HIP_MEMORY_SCOPE_AGENT);
}

// Weight prep: g_wtp[p][((ci*3+ky)*3+kx)*64+co]; passes 4,5 spatially
// transposed. Also zeroes all sync flags.
__global__ __launch_bounds__(256) void prep(
    const float* __restrict__ w0, const float* __restrict__ w1,
    const float* __restrict__ w2, const float* __restrict__ w3,
    const float* __restrict__ w4, const float* __restrict__ w5)
{
    int gid = blockIdx.x * 256 + threadIdx.x;
    if (gid < NFLAG) g_flags[gid] = 0;
    if (gid >= 6 * WTP_PASS) return;
    int p  = gid / WTP_PASS;
    int r  = gid % WTP_PASS;
    int co = r & 63;
    int q  = r >> 6;          // ci*9 + ky*3 + kx
    int kx = q % 3;
    int t2 = q / 3;
    int ky = t2 % 3;
    int ci = t2 / 3;
    const float* src = (p==0)?w0:(p==1)?w1:(p==2)?w2:(p==3)?w3:(p==4)?w4:w5;
    g_wtp[gid] = (p < 4) ? src[co*576 + ci*9 + ky*3 + kx]
                         : src[co*576 + ci*9 + kx*3 + ky];
}

__global__ __launch_bounds__(256) void transpose_hw(
    const float* __restrict__ in, float* __restrict__ out)
{
    __shared__ float t[64][65];
    const size_t base = (size_t)blockIdx.x * 4096;
    const int c  = threadIdx.x & 63;
    const int r4 = threadIdx.x >> 6;
#pragma unroll
    for (int r = 0; r < 16; ++r) {
        int a = r4 * 16 + r;
        t[a][c] = in[base + a * 64 + c];
    }
    __syncthreads();
#pragma unroll
    for (int r = 0; r < 16; ++r) {
        int bb = r4 * 16 + r;
        out[base + (size_t)bb * 64 + c] = t[c][bb];
    }
}

// Persistent per-pass scan. Block = 4x4 px x 64 ch; 8 waves, wave = 8-ci chunk
// (lane = co, weights in VGPRs). Recurrence tile lives in LDS; only the 20-px
// halo ring goes through the L3-coherent exchange. buf accesses are plain.
__global__ __launch_bounds__(512, 2) void pass_kernel(
    float* __restrict__ buf, const float* __restrict__ wtp,
    unsigned* __restrict__ flags, float* __restrict__ exch,
    int st, int su, int dir)
{
    __shared__ float lds[21504];      // 84 KB -> exactly 1 block/CU
    float* reg = lds;                 // [6 row][64 ci][10 pad] region (y[t-1])
    float* red = lds + 4096;          // [8 wave][16 px][64 lane] partials

    const int tid  = threadIdx.x;
    const int lane = tid & 63;
    const int wv   = tid >> 6;        // 0..7
    const int b    = blockIdx.x;
    const int bu   = b >> 4, bv = b & 15;
    const int u0   = bu << 2, v0 = bv << 2;
    const int rr   = wv >> 1, cc0 = (wv & 1) * 2;   // this wave's output px pair
    const int p0   = wv * 2;

    // per-lane weights for this wave's 8 ci
    float W[8][3][3];
#pragma unroll
    for (int i = 0; i < 8; ++i)
#pragma unroll
        for (int ky = 0; ky < 3; ++ky)
#pragma unroll
            for (int kx = 0; kx < 3; ++kx)
                W[i][ky][kx] = wtp[(((wv*8 + i)*3 + ky)*3 + kx)*64 + lane];

    // lanes 0..7 of wave 0 each own one spatial neighbor's flag
    int nbr = -1;
    if (lane < 8) {
        int c  = lane + (lane >= 4 ? 1 : 0);   // skip center of 3x3
        int nu = bu + c/3 - 1, nv = bv + c%3 - 1;
        if (nu >= 0 && nu < 16 && nv >= 0 && nv < 16) nbr = (nu*16 + nv)*16;
    }

    for (int s = 1; s <= 63; ++s) {
        const int t  = (dir > 0) ? s : 63 - s;
        const int tp = t - dir;

        if (wv == 0 && s > 1) {
            const unsigned tgt = (unsigned)(s - 1);
            bool ok = (nbr < 0);
            if (!ok) ok = __hip_atomic_load(&flags[nbr], __ATOMIC_RELAXED,
                                            __HIP_MEMORY_SCOPE_AGENT) >= tgt;
            int spins = 0;
            while (!__all(ok) && spins < (1 << 22)) {
                __builtin_amdgcn_s_sleep(1);
                if (!ok) ok = __hip_atomic_load(&flags[nbr], __ATOMIC_RELAXED,
                                                __HIP_MEMORY_SCOPE_AGENT) >= tgt;
                ++spins;
            }
        }
        __syncthreads();   // B0: halo published by all neighbors

        // x[t] prefetch (plain cached; nobody writes my px of slice t)
        const float2 xv = *(const float2*)(buf + (size_t)t*st
                          + (size_t)lane*CI_STRIDE + (size_t)(u0+rr)*su + (v0+cc0));

        // stage halo ring into reg (interior already in LDS from last step)
        if (s == 1) {
            // full 6x6 region from buf slice t0 (plain loads, fresh at dispatch)
            for (int k = wv; k < 36; k += 8) {
                const int row = k / 6, col = k % 6;
                const int gu = u0 - 1 + row, gv = v0 - 1 + col;
                float v = 0.f;
                if (gu >= 0 && gu < 64 && gv >= 0 && gv < 64)
                    v = buf[(size_t)tp*st + (size_t)lane*CI_STRIDE
                            + (size_t)gu*su + gv];
                reg[(row*64 + lane)*10 + col] = v;
            }
        } else {
            const int parity = (s - 1) & 1;
            for (int k = wv; k < 20; k += 8) {
                const int row = HROW[k], col = HCOL[k];
                const int du = (row==0)?-1:(row==5)?1:0;
                const int dv = (col==0)?-1:(col==5)?1:0;
                const int nu = bu + du, nv = bv + dv;
                if (nu >= 0 && nu < 16 && nv >= 0 && nv < 16) {
                    const int lr = (row==0)?3:(row==5)?0:row-1;
                    const int lc = (col==0)?3:(col==5)?0:col-1;
                    float v = ald(exch + (((size_t)parity*256 + (nu*16+nv))*16
                                          + (lr*4+lc))*64 + lane);
                    reg[(row*64 + lane)*10 + col] = v;
                }   // invalid neighbors: ring px stay 0 from s==1 init
            }
        }
        __syncthreads();   // B1: region complete

        float acc[16];
#pragma unroll
        for (int p = 0; p < 16; ++p) acc[p] = 0.f;

#pragma unroll
        for (int i = 0; i < 8; ++i) {
            const int ci = wv*8 + i;
            float win[6][6];
#pragma unroll
            for (int r = 0; r < 6; ++r) {
                const float2* rp = (const float2*)&reg[(r*64 + ci)*10];
                float2 a = rp[0], m = rp[1], d = rp[2];
                win[r][0] = a.x; win[r][1] = a.y; win[r][2] = m.x;
                win[r][3] = m.y; win[r][4] = d.x; win[r][5] = d.y;
            }
#pragma unroll
            for (int oi = 0; oi < 4; ++oi)
#pragma unroll
                for (int ky = 0; ky < 3; ++ky) {
                    const float k0 = W[i][ky][0], k1 = W[i][ky][1], k2 = W[i][ky][2];
#pragma unroll
                    for (int oj = 0; oj < 4; ++oj)
                        acc[oi*4+oj] = fmaf(win[oi+ky][oj],   k0,
                                       fmaf(win[oi+ky][oj+1], k1,
                                       fmaf(win[oi+ky][oj+2], k2, acc[oi*4+oj])));
                }
        }

#pragma unroll
        for (int p = 0; p < 16; ++p)
            red[(wv*16 + p)*64 + lane] = acc[p];
        __syncthreads();   // B2: partials ready

        float s0 = 0.f, s1 = 0.f;
#pragma unroll
        for (int g = 0; g < 8; ++g) {
            s0 += red[(g*16 + p0    )*64 + lane];
            s1 += red[(g*16 + p0 + 1)*64 + lane];
        }
        const float o0 = xv.x + fmaxf(s0, 0.f);
        const float o1 = xv.y + fmaxf(s1, 0.f);

        // plain store to buf (read only after kernel boundary)
        *(float2*)(buf + (size_t)t*st + (size_t)lane*CI_STRIDE
                   + (size_t)(u0+rr)*su + (v0+cc0)) = make_float2(o0, o1);
        // coherent publish of packed tile (parity slot s&1)
        float* eb = exch + ((size_t)(s & 1)*256 + b)*1024;
        ast(eb + (p0    )*64 + lane, o0);
        ast(eb + (p0 + 1)*64 + lane, o1);
        // update LDS region interior for next step
        reg[((rr+1)*64 + lane)*10 + (cc0+1)] = o0;
        reg[((rr+1)*64 + lane)*10 + (cc0+2)] = o1;
        __syncthreads();   // B3: drains exch stores (vmcnt) in every wave

        if (tid == 0)
            __hip_atomic_store(&flags[b*16], (unsigned)s, __ATOMIC_RELAXED,
                               __HIP_MEMORY_SCOPE_AGENT);
    }
}

extern "C" void kernel_launch(void* const* d_in, const int* in_sizes, int n_in,
                              void* d_out, int out_size, void* d_ws, size_t ws_size,
                              hipStream_t stream)
{
    (void)in_sizes; (void)n_in; (void)out_size; (void)d_ws; (void)ws_size;
    const float* x = (const float*)d_in[0];
    float* out = (float*)d_out;

    void *pa, *pb, *pw, *pf, *pe;
    hipGetSymbolAddress(&pa, HIP_SYMBOL(g_bufA));
    hipGetSymbolAddress(&pb, HIP_SYMBOL(g_bufB));
    hipGetSymbolAddress(&pw, HIP_SYMBOL(g_wtp));
    hipGetSymbolAddress(&pf, HIP_SYMBOL(g_flags));
    hipGetSymbolAddress(&pe, HIP_SYMBOL(g_exch));
    float* A = (float*)pa + 16;
    float* B = (float*)pb + 16;
    float* wtp = (float*)pw;
    unsigned* flags = (unsigned*)pf;
    float* exch = (float*)pe;

    prep<<<864, 256, 0, stream>>>(
        (const float*)d_in[1], (const float*)d_in[2], (const float*)d_in[3],
        (const float*)d_in[4], (const float*)d_in[5], (const float*)d_in[6]);

    hipMemcpyAsync(A, x, (size_t)NELEM * sizeof(float),
                   hipMemcpyDeviceToDevice, stream);

    // layout0 [k][d][h][w]: UD/DU: t=h (st 64), u=d (su 4096), v=w
    pass_kernel<<<256, 512, 0, stream>>>(A, wtp + 0*WTP_PASS, flags + 0*4096, exch, 64, 4096, +1);
    pass_kernel<<<256, 512, 0, stream>>>(A, wtp + 1*WTP_PASS, flags + 1*4096, exch, 64, 4096, -1);

    transpose_hw<<<4096, 256, 0, stream>>>(A, B);   // -> layout1 [k][d][w][h]

    // LR/RL: t=w (st 64), u=d (su 4096), v=h
    pass_kernel<<<256, 512, 0, stream>>>(B, wtp + 2*WTP_PASS, flags + 2*4096, exch, 64, 4096, +1);
    pass_kernel<<<256, 512, 0, stream>>>(B, wtp + 3*WTP_PASS, flags + 3*4096, exch, 64, 4096, -1);
    // FB/BF: t=d (st 4096), u=w (su 64), v=h; weights spatially transposed
    pass_kernel<<<256, 512, 0, stream>>>(B, wtp + 4*WTP_PASS, flags + 4*4096, exch, 4096, 64, +1);
    pass_kernel<<<256, 512, 0, stream>>>(B, wtp + 5*WTP_PASS, flags + 5*4096, exch, 4096, 64, -1);

    transpose_hw<<<4096, 256, 0, stream>>>(B, out);
}

// Round 7
// 2489.578 us; speedup vs baseline: 18.5298x; 1.2625x over previous
//
#include <hip/hip_runtime.h>

#define NELEM     16777216   // 64^4
#define CI_STRIDE 262144     // 64^3
#define WTP_PASS  36864      // 64ci * 3 * 3 * 64co
#define NFLAG     (6 * 256 * 16)
#define EX_PAR    262144     // 256 blocks * 16 px * 64 ch (one parity slot)

__device__ float    g_bufA[NELEM + 32];
__device__ float    g_bufB[NELEM + 32];
__device__ float    g_wtp[6 * WTP_PASS];
__device__ float    g_exch[2 * EX_PAR];
__device__ unsigned g_flags[NFLAG];

static __device__ __forceinline__ float ald(const float* p) {
    return __hip_atomic_load(p, __ATOMIC_RELAXED, __HIP_MEMORY_SCOPE_AGENT);
}
static __device__ __forceinline__ void ast(float* p, float v) {
    __hip_atomic_store(p, v, __ATOMIC_RELAXED, __HIP_MEMORY_SCOPE_AGENT);
}
static __device__ __forceinline__ float g4(const float4 v, int i) {
    switch (i) { case 0: return v.x; case 1: return v.y;
                 case 2: return v.z; default: return v.w; }
}

// ring cell k -> (row,col) in the 6x6 window
static __device__ __forceinline__ void kmap(int k, int& row, int& col) {
    if      (k < 4)  { row = 0;    col = k;      }
    else if (k < 8)  { row = 5;    col = k - 4;  }
    else if (k < 12) { row = k-7;  col = 0;      }
    else if (k < 16) { row = k-11; col = 5;      }
    else if (k < 18) { row = 0;    col = k - 12; }
    else             { row = 5;    col = k - 14; }
}

__global__ __launch_bounds__(256) void prep(
    const float* __restrict__ w0, const float* __restrict__ w1,
    const float* __restrict__ w2, const float* __restrict__ w3,
    const float* __restrict__ w4, const float* __restrict__ w5)
{
    int gid = blockIdx.x * 256 + threadIdx.x;
    if (gid < NFLAG) g_flags[gid] = 0;
    if (gid >= 6 * WTP_PASS) return;
    int p  = gid / WTP_PASS;
    int r  = gid % WTP_PASS;
    int co = r & 63;
    int q  = r >> 6;          // ci*9 + ky*3 + kx
    int kx = q % 3;
    int t2 = q / 3;
    int ky = t2 % 3;
    int ci = t2 / 3;
    const float* src = (p==0)?w0:(p==1)?w1:(p==2)?w2:(p==3)?w3:(p==4)?w4:w5;
    g_wtp[gid] = (p < 4) ? src[co*576 + ci*9 + ky*3 + kx]
                         : src[co*576 + ci*9 + kx*3 + ky];
}

__global__ __launch_bounds__(256) void transpose_hw(
    const float* __restrict__ in, float* __restrict__ out)
{
    __shared__ float t[64][65];
    const size_t base = (size_t)blockIdx.x * 4096;
    const int c  = threadIdx.x & 63;
    const int r4 = threadIdx.x >> 6;
#pragma unroll
    for (int r = 0; r < 16; ++r) {
        int a = r4 * 16 + r;
        t[a][c] = in[base + a * 64 + c];
    }
    __syncthreads();
#pragma unroll
    for (int r = 0; r < 16; ++r) {
        int bb = r4 * 16 + r;
        out[base + (size_t)bb * 64 + c] = t[c][bb];
    }
}

// Persistent per-pass scan. Block = 4x4 px x 64 ch; 8 waves x 8-ci chunk
// (lane = co, weights in VGPRs). r5-proven sync protocol (wave0 polls all 8
// neighbors -> B0 barrier -> exchange reads); PhaseA (own-tile taps, 100/144)
// overlaps the in-flight exchange loads; PhaseB adds the 44 ring taps.
__global__ __launch_bounds__(512, 2) void pass_kernel(
    float* __restrict__ buf, const float* __restrict__ wtp,
    unsigned* __restrict__ flags, float* __restrict__ exch,
    int st, int su, int dir)
{
    __shared__ float lds[21504];   // 84 KB -> exactly 1 block/CU (all resident)
    float* rint = lds;             // [4 row][64 ci][4 col] own tile y[prev]
    float* ring = lds + 1024;      // [64 ci][24] halo cells (k-layout)
    float* red  = lds + 2560;      // [8 wv][16 px][64 lane] partials

    const int tid  = threadIdx.x;
    const int lane = tid & 63;
    const int wv   = tid >> 6;     // 0..7
    // XCD swizzle: u-row neighbors share an XCD (bijective relabel of blocks)
    const int B  = blockIdx.x;
    const int bu = ((B & 7) << 1) | ((B >> 7) & 1);
    const int bv = (B >> 3) & 15;
    const int b  = bu * 16 + bv;
    const int u0 = bu << 2, v0 = bv << 2;
    const int rr = wv >> 1, cc0 = (wv & 1) << 1;   // this wave's output px pair
    const int p0 = wv << 1;

    // per-lane weights for this wave's 8 ci
    float W[8][3][3];
#pragma unroll
    for (int i = 0; i < 8; ++i)
#pragma unroll
        for (int ky = 0; ky < 3; ++ky)
#pragma unroll
            for (int kx = 0; kx < 3; ++kx)
                W[i][ky][kx] = wtp[(((wv*8 + i)*3 + ky)*3 + kx)*64 + lane];

    // wave 0, lanes 0..7: one spatial neighbor flag each (poll set)
    int nbr = -1;
    if (lane < 8) {
        int c  = lane + (lane >= 4 ? 1 : 0);   // skip center of 3x3
        int nu = bu + c/3 - 1, nv = bv + c%3 - 1;
        if (nu >= 0 && nu < 16 && nv >= 0 && nv < 16) nbr = (nu*16 + nv)*16;
    }

    // staging tables: this wave's ring cells (k = wv, wv+8, wv+16)
    int kk0=-1, kk1=-1, kk2=-1, so0=0, so1=0, so2=0;
#pragma unroll
    for (int j = 0; j < 3; ++j) {
        int k = wv + 8*j;
        if (k >= 20) continue;
        int row, col; kmap(k, row, col);
        int du = (row==0)?-1:(row==5)?1:0, dv = (col==0)?-1:(col==5)?1:0;
        int nu = bu + du, nv = bv + dv;
        if (nu < 0 || nu > 15 || nv < 0 || nv > 15) continue;
        int nb = nu*16 + nv;
        int lr = (row==0)?3:(row==5)?0:row-1;
        int lc = (col==0)?3:(col==5)?0:col-1;
        int so = (nb*16 + lr*4 + lc)*64 + lane;
        if      (j == 0) { kk0 = k; so0 = so; }
        else if (j == 1) { kk1 = k; so1 = so; }
        else             { kk2 = k; so2 = so; }
    }

    // prologue: y[t0] own tile + ring from buf (plain, fresh at dispatch)
    const int t0 = (dir > 0) ? 0 : 63;
    {
        const float2 iv = *(const float2*)(buf + (size_t)t0*st
              + (size_t)lane*CI_STRIDE + (size_t)(u0+rr)*su + (v0+cc0));
        *(float2*)&rint[(rr*64 + lane)*4 + cc0] = iv;
    }
#pragma unroll
    for (int j = 0; j < 3; ++j) {
        int k = wv + 8*j;
        if (k >= 20) continue;
        int row, col; kmap(k, row, col);
        int gu = u0 - 1 + row, gv = v0 - 1 + col;
        float v = 0.f;
        if (gu >= 0 && gu < 64 && gv >= 0 && gv < 64)
            v = buf[(size_t)t0*st + (size_t)lane*CI_STRIDE + (size_t)gu*su + gv];
        ring[lane*24 + k] = v;
    }
    __syncthreads();

    for (int s = 1; s <= 63; ++s) {
        const int t = (dir > 0) ? s : 63 - s;

        // wave 0 polls all 8 neighbor flags for step s-1 (throttled)
        if (wv == 0 && s > 1) {
            const unsigned tgt = (unsigned)(s - 1);
            bool ok = (nbr < 0);
            if (!ok) ok = __hip_atomic_load(&flags[nbr], __ATOMIC_RELAXED,
                                            __HIP_MEMORY_SCOPE_AGENT) >= tgt;
            int spins = 0;
            while (!__all(ok) && spins < (1 << 22)) {
                __builtin_amdgcn_s_sleep(1);
                if (!ok) ok = __hip_atomic_load(&flags[nbr], __ATOMIC_RELAXED,
                                                __HIP_MEMORY_SCOPE_AGENT) >= tgt;
                ++spins;
            }
        }
        __syncthreads();   // B0: all neighbor halos for step s-1 published

        // x[t] prefetch (plain cached; nobody else writes my px of slice t)
        const float2 xv = *(const float2*)(buf + (size_t)t*st
              + (size_t)lane*CI_STRIDE + (size_t)(u0+rr)*su + (v0+cc0));

        // issue exchange loads now (latency overlaps PhaseA below)
        float c0 = 0.f, c1 = 0.f, c2 = 0.f;
        if (s > 1) {
            const float* xsrc = exch + (size_t)((s-1) & 1) * EX_PAR;
            if (kk0 >= 0) c0 = ald(xsrc + so0);
            if (kk1 >= 0) c1 = ald(xsrc + so1);
            if (kk2 >= 0) c2 = ald(xsrc + so2);
        }

        float acc[16];
#pragma unroll
        for (int p = 0; p < 16; ++p) acc[p] = 0.f;

        // PHASE A: taps whose window cell is in the own tile (100/144)
#pragma unroll
        for (int i = 0; i < 8; ++i) {
            const int ci = wv*8 + i;
            const float4 R0 = *(const float4*)&rint[(0*64 + ci)*4];
            const float4 R1 = *(const float4*)&rint[(1*64 + ci)*4];
            const float4 R2 = *(const float4*)&rint[(2*64 + ci)*4];
            const float4 R3 = *(const float4*)&rint[(3*64 + ci)*4];
#pragma unroll
            for (int oi = 0; oi < 4; ++oi)
#pragma unroll
            for (int ky = 0; ky < 3; ++ky) {
                const int wr = oi + ky;
                if (wr < 1 || wr > 4) continue;
                const float4 Rw = (wr==1)?R0:(wr==2)?R1:(wr==3)?R2:R3;
#pragma unroll
                for (int oj = 0; oj < 4; ++oj)
#pragma unroll
                for (int kx = 0; kx < 3; ++kx) {
                    const int wc = oj + kx;
                    if (wc < 1 || wc > 4) continue;
                    acc[oi*4+oj] = fmaf(W[i][ky][kx], g4(Rw, wc-1), acc[oi*4+oj]);
                }
            }
        }

        // land the staged ring cells in LDS (loads have drained by now)
        if (s > 1) {
            if (kk0 >= 0) ring[lane*24 + kk0] = c0;
            if (kk1 >= 0) ring[lane*24 + kk1] = c1;
            if (kk2 >= 0) ring[lane*24 + kk2] = c2;
        }
        __syncthreads();   // B1: ring complete

        // PHASE B: ring taps (44/144)
#pragma unroll
        for (int i = 0; i < 8; ++i) {
            const int ci = wv*8 + i;
            const float4 r0a = *(const float4*)&ring[ci*24 + 0];
            const float4 r5a = *(const float4*)&ring[ci*24 + 4];
            const float4 cl  = *(const float4*)&ring[ci*24 + 8];
            const float4 cr  = *(const float4*)&ring[ci*24 + 12];
            const float2 r0b = *(const float2*)&ring[ci*24 + 16];
            const float2 r5b = *(const float2*)&ring[ci*24 + 18];
#pragma unroll
            for (int oi = 0; oi < 4; ++oi)
#pragma unroll
            for (int ky = 0; ky < 3; ++ky) {
                const int wr = oi + ky;
#pragma unroll
                for (int oj = 0; oj < 4; ++oj)
#pragma unroll
                for (int kx = 0; kx < 3; ++kx) {
                    const int wc = oj + kx;
                    if (wr >= 1 && wr <= 4 && wc >= 1 && wc <= 4) continue;
                    float cell;
                    if      (wr == 0) cell = (wc < 4) ? g4(r0a, wc)
                                             : (wc == 4 ? r0b.x : r0b.y);
                    else if (wr == 5) cell = (wc < 4) ? g4(r5a, wc)
                                             : (wc == 4 ? r5b.x : r5b.y);
                    else if (wc == 0) cell = g4(cl, wr-1);
                    else              cell = g4(cr, wr-1);
                    acc[oi*4+oj] = fmaf(W[i][ky][kx], cell, acc[oi*4+oj]);
                }
            }
        }

        // partials -> LDS
#pragma unroll
        for (int p = 0; p < 16; ++p)
            red[(wv*16 + p)*64 + lane] = acc[p];
        __syncthreads();   // B2

        float s0 = 0.f, s1 = 0.f;
#pragma unroll
        for (int g = 0; g < 8; ++g) {
            s0 += red[(g*16 + p0    )*64 + lane];
            s1 += red[(g*16 + p0 + 1)*64 + lane];
        }
        const float o0 = xv.x + fmaxf(s0, 0.f);
        const float o1 = xv.y + fmaxf(s1, 0.f);

        // output to buf (plain; read only after kernel boundary)
        *(float2*)(buf + (size_t)t*st + (size_t)lane*CI_STRIDE
                   + (size_t)(u0+rr)*su + (v0+cc0)) = make_float2(o0, o1);
        if (s < 63) {
            // next step's own tile (LDS) + coherent border publish
            *(float2*)&rint[(rr*64 + lane)*4 + cc0] = make_float2(o0, o1);
            float* eb = exch + (size_t)(s & 1)*EX_PAR + b*1024;
            ast(eb + (p0    )*64 + lane, o0);
            ast(eb + (p0 + 1)*64 + lane, o1);
        }
        __syncthreads();   // B3: drains all waves' stores before flag publish

        if (s < 63 && tid == 0)
            __hip_atomic_store(&flags[b*16], (unsigned)s, __ATOMIC_RELAXED,
                               __HIP_MEMORY_SCOPE_AGENT);
    }
}

extern "C" void kernel_launch(void* const* d_in, const int* in_sizes, int n_in,
                              void* d_out, int out_size, void* d_ws, size_t ws_size,
                              hipStream_t stream)
{
    (void)in_sizes; (void)n_in; (void)out_size; (void)d_ws; (void)ws_size;
    const float* x = (const float*)d_in[0];
    float* out = (float*)d_out;

    void *pa, *pb, *pw, *pf, *pe;
    hipGetSymbolAddress(&pa, HIP_SYMBOL(g_bufA));
    hipGetSymbolAddress(&pb, HIP_SYMBOL(g_bufB));
    hipGetSymbolAddress(&pw, HIP_SYMBOL(g_wtp));
    hipGetSymbolAddress(&pf, HIP_SYMBOL(g_flags));
    hipGetSymbolAddress(&pe, HIP_SYMBOL(g_exch));
    float* A  = (float*)pa + 16;
    float* Bb = (float*)pb + 16;
    float* wtp = (float*)pw;
    unsigned* flags = (unsigned*)pf;
    float* exch = (float*)pe;

    prep<<<864, 256, 0, stream>>>(
        (const float*)d_in[1], (const float*)d_in[2], (const float*)d_in[3],
        (const float*)d_in[4], (const float*)d_in[5], (const float*)d_in[6]);

    hipMemcpyAsync(A, x, (size_t)NELEM * sizeof(float),
                   hipMemcpyDeviceToDevice, stream);

    // layout0 [k][d][h][w]: UD/DU: t=h (st 64), u=d (su 4096), v=w
    pass_kernel<<<256, 512, 0, stream>>>(A, wtp + 0*WTP_PASS, flags + 0*4096, exch, 64, 4096, +1);
    pass_kernel<<<256, 512, 0, stream>>>(A, wtp + 1*WTP_PASS, flags + 1*4096, exch, 64, 4096, -1);

    transpose_hw<<<4096, 256, 0, stream>>>(A, Bb);   // -> layout1 [k][d][w][h]

    // LR/RL: t=w (st 64), u=d (su 4096), v=h
    pass_kernel<<<256, 512, 0, stream>>>(Bb, wtp + 2*WTP_PASS, flags + 2*4096, exch, 64, 4096, +1);
    pass_kernel<<<256, 512, 0, stream>>>(Bb, wtp + 3*WTP_PASS, flags + 3*4096, exch, 64, 4096, -1);
    // FB/BF: t=d (st 4096), u=w (su 64), v=h; weights spatially transposed
    pass_kernel<<<256, 512, 0, stream>>>(Bb, wtp + 4*WTP_PASS, flags + 4*4096, exch, 4096, 64, +1);
    pass_kernel<<<256, 512, 0, stream>>>(Bb, wtp + 5*WTP_PASS, flags + 5*4096, exch, 4096, 64, -1);

    transpose_hw<<<4096, 256, 0, stream>>>(Bb, out);
}